// Round 8
// baseline (243.452 us; speedup 1.0000x reference)
//
#include <hip/hip_runtime.h>
#include <hip/hip_bf16.h>

// CausalSelfAttention  B=4, T=2048, C=1024, NH=16, HD=64
// fp32 in/out buffers; bf16 MFMA internally; fp32 accumulation.
//
//   0. cvt3: x, w_attn, w_proj -> bf16 (one kernel)
//   1. GEMM1: 32x32x16 MFMA, global_load_lds, DOUBLE-BUFFERED LDS with one
//      barrier per K-iter (prefetch overlaps MFMA); epilogue: Q (pre-scaled
//      0.125*log2e), K -> qk[t][2048], V^T -> vt[b][h][d][t]
//   2. attn4: flash attention, 128 q-rows/block, static-max exp2 softmax,
//      l via ones-column; Ps column-rotated by quad*16 (bank-conflict-free)
//   3. GEMM3: same structure as GEMM1, fp32 C

typedef __attribute__((ext_vector_type(8))) short bf16x8;
typedef __attribute__((ext_vector_type(4))) float f32x4;
typedef __attribute__((ext_vector_type(16))) float f32x16;
typedef unsigned short ushort_t;

#if __has_builtin(__builtin_amdgcn_exp2f)
#define EXP2(x) __builtin_amdgcn_exp2f(x)
#else
#define EXP2(x) exp2f(x)
#endif

__device__ inline ushort_t f2bf(float f) {
    union { float f; unsigned int u; } x; x.f = f;
    return (ushort_t)((x.u + 0x7fffu + ((x.u >> 16) & 1u)) >> 16);
}

// cheap round-half-up bf16 (P >= 0, never NaN)
__device__ inline ushort_t f2bf_fast(float f) {
    union { float f; unsigned int u; } x; x.f = f;
    return (ushort_t)((x.u + 0x8000u) >> 16);
}

__device__ inline bf16x8 load8_f32_to_bf16(const float* p) {
    float4 f0 = *(const float4*)p;
    float4 f1 = *(const float4*)(p + 4);
    bf16x8 r;
    r[0] = (short)f2bf(f0.x); r[1] = (short)f2bf(f0.y);
    r[2] = (short)f2bf(f0.z); r[3] = (short)f2bf(f0.w);
    r[4] = (short)f2bf(f1.x); r[5] = (short)f2bf(f1.y);
    r[6] = (short)f2bf(f1.z); r[7] = (short)f2bf(f1.w);
    return r;
}

// async global->LDS, 16B per lane; lds base must be wave-uniform
__device__ inline void gl2lds16(const ushort_t* g, ushort_t* l) {
    __builtin_amdgcn_global_load_lds(
        (const __attribute__((address_space(1))) unsigned int*)g,
        (__attribute__((address_space(3))) unsigned int*)l,
        16, 0, 0);
}

__global__ void cvt3(const float* __restrict__ a, long n8a,
                     const float* __restrict__ b, long n8b,
                     const float* __restrict__ c, long n8c,
                     ushort_t* __restrict__ out) {
    long i = (long)blockIdx.x * 256 + threadIdx.x;
    const float* src; long off;
    if (i < n8a) { src = a; off = i; }
    else if (i < n8a + n8b) { src = b; off = i - n8a; }
    else if (i < n8a + n8b + n8c) { src = c; off = i - n8a - n8b; }
    else return;
    *(bf16x8*)(out + i * 8) = load8_f32_to_bf16(src + off * 8);
}

__global__ void fill_zero_f32(float* out, int n) {
    int i = blockIdx.x * 256 + threadIdx.x;
    if (i < n) out[i] = 0.0f;
}

#define BM 128
#define BN 128
#define BK 64

#define QK_LOG2E_SCALE 0.18033688011112042f   // 0.125 * log2(e)

// ---------------------------------------------------------------------------
// NT GEMM: bf16 A/B, 128x128 tile, BK=64, 32x32x16 MFMA (2x2 per wave).
// Double-buffered LDS: one __syncthreads per K-iter; barrier drains tile-k
// loads (which had all of compute(k-1) to land), then tile-(k+1) loads are
// issued into the other buffer and stay in flight through compute(k).
// EPI: 1 = fp32 C, 2 = qkv split (Q scaled, K -> qk; V^T -> vt)
// ---------------------------------------------------------------------------
template <int EPI>
__global__ __launch_bounds__(256) void gemm_lds(
        const ushort_t* __restrict__ A, const ushort_t* __restrict__ B,
        void* __restrict__ Cp, void* __restrict__ Cp2,
        int M, int N, int K) {
    __shared__ ushort_t As[2][BM * BK];
    __shared__ ushort_t Bs[2][BN * BK];

    const int tid  = threadIdx.x;
    const int lane = tid & 63;
    const int w    = tid >> 6;
    const int l31  = lane & 31;
    const int half = lane >> 5;

    const int bm = blockIdx.y * BM;
    const int bn = blockIdx.x * BN;
    const int wm = (w & 1) * 64;
    const int wn = (w >> 1) * 64;

    const int lr8 = lane >> 3;
    const int cbg = ((lane & 7) ^ lr8) * 8;
    const ushort_t* Aw = A + (size_t)(bm + w * 32 + lr8) * K + cbg;
    const ushort_t* Bw = B + (size_t)(bn + w * 32 + lr8) * K + cbg;

    auto issue = [&](int buf, int k0) {
#pragma unroll
        for (int j = 0; j < 4; j++) {
            gl2lds16(Aw + (size_t)(j * 8) * K + k0, &As[buf][(w * 32 + j * 8) * BK]);
            gl2lds16(Bw + (size_t)(j * 8) * K + k0, &Bs[buf][(w * 32 + j * 8) * BK]);
        }
    };

    f32x16 acc[2][2] = {};

    issue(0, 0);
    const int nIt = K / BK;
    for (int k = 0; k < nIt; k++) {
        const int cur = k & 1;
        __syncthreads();                    // drain tile-k loads; also: everyone
                                            // done reading buf cur^1 last iter
        if (k + 1 < nIt) issue(cur ^ 1, (k + 1) * BK);

#pragma unroll
        for (int s = 0; s < 4; s++) {       // K=16 per step
            const int cs = (((2 * s + half) ^ (lane & 7)) * 8);
            bf16x8 af[2], bfr[2];
#pragma unroll
            for (int i = 0; i < 2; i++)
                af[i] = *(const bf16x8*)&As[cur][(wm + i * 32 + l31) * BK + cs];
#pragma unroll
            for (int i = 0; i < 2; i++)
                bfr[i] = *(const bf16x8*)&Bs[cur][(wn + i * 32 + l31) * BK + cs];
#pragma unroll
            for (int mi = 0; mi < 2; mi++)
#pragma unroll
                for (int ni = 0; ni < 2; ni++)
                    acc[mi][ni] = __builtin_amdgcn_mfma_f32_32x32x16_bf16(
                        af[mi], bfr[ni], acc[mi][ni], 0, 0, 0);
        }
    }

    // epilogue: 32x32 C/D layout: col=lane&31, row=(r&3)+8*(r>>2)+4*half
#pragma unroll
    for (int mi = 0; mi < 2; mi++)
#pragma unroll
        for (int ni = 0; ni < 2; ni++) {
            const int colg = bn + wn + ni * 32 + l31;
            if constexpr (EPI == 1) {
                float* cb = (float*)Cp + colg;
#pragma unroll
                for (int r = 0; r < 16; r++) {
                    const int row = bm + wm + mi * 32 + (r & 3) + 8 * (r >> 2) + 4 * half;
                    cb[(size_t)row * N] = acc[mi][ni][r];
                }
            } else {
                if (colg < 2048) {
                    const float qs = (colg < 1024) ? QK_LOG2E_SCALE : 1.0f;
                    ushort_t* cb = (ushort_t*)Cp + colg;
#pragma unroll
                    for (int r = 0; r < 16; r++) {
                        const int row = bm + wm + mi * 32 + (r & 3) + 8 * (r >> 2) + 4 * half;
                        cb[(size_t)row * 2048] = f2bf(acc[mi][ni][r] * qs);
                    }
                } else {
                    const int vc = colg - 2048;
                    const int hh = vc >> 6, dd = vc & 63;
                    ushort_t* vtp = (ushort_t*)Cp2 + ((size_t)hh * 64 + dd) * 2048;
#pragma unroll
                    for (int r = 0; r < 16; r++) {
                        const int row = bm + wm + mi * 32 + (r & 3) + 8 * (r >> 2) + 4 * half;
                        const int bb = row >> 11, tt = row & 2047;
                        vtp[(size_t)bb * 16 * 64 * 2048 + tt] = f2bf(acc[mi][ni][r]);
                    }
                }
            }
        }
}

// ---------------------------------------------------------------------------
// Fallback register-staging NT GEMM (fp32 operands), only if ws too small.
// ---------------------------------------------------------------------------
#define LDK 72

template <bool A_F32, bool B_F32, int EPI>
__global__ __launch_bounds__(256) void gemm_nt(
        const void* __restrict__ Ap, const void* __restrict__ Bp,
        void* __restrict__ Cp, void* __restrict__ Cp2,
        int M, int N, int K) {
    __shared__ ushort_t As[BM * LDK];
    __shared__ ushort_t Bs[BN * LDK];

    const int tid  = threadIdx.x;
    const int lane = tid & 63;
    const int w    = tid >> 6;
    const int quad = lane >> 4;
    const int l16  = lane & 15;

    const int bm = blockIdx.y * BM;
    const int bn = blockIdx.x * BN;
    const int wm = (w & 1) * 64;
    const int wn = (w >> 1) * 64;

    f32x4 acc[4][4] = {};

    const int lrow = tid >> 3;
    const int lcol = (tid & 7) * 8;

    bf16x8 pa[4], pb[4];
#pragma unroll
    for (int i = 0; i < 4; i++) {
        const int ra = lrow + i * 32;
        if constexpr (A_F32)
            pa[i] = load8_f32_to_bf16((const float*)Ap + (size_t)(bm + ra) * K + lcol);
        else
            pa[i] = *(const bf16x8*)((const ushort_t*)Ap + (size_t)(bm + ra) * K + lcol);
        if constexpr (B_F32)
            pb[i] = load8_f32_to_bf16((const float*)Bp + (size_t)(bn + ra) * K + lcol);
        else
            pb[i] = *(const bf16x8*)((const ushort_t*)Bp + (size_t)(bn + ra) * K + lcol);
    }

    for (int k0 = 0; k0 < K; k0 += BK) {
        __syncthreads();
#pragma unroll
        for (int i = 0; i < 4; i++) {
            *(bf16x8*)&As[(lrow + i * 32) * LDK + lcol] = pa[i];
            *(bf16x8*)&Bs[(lrow + i * 32) * LDK + lcol] = pb[i];
        }
        __syncthreads();

        if (k0 + BK < K) {
            const int kn = k0 + BK + lcol;
#pragma unroll
            for (int i = 0; i < 4; i++) {
                const int ra = lrow + i * 32;
                if constexpr (A_F32)
                    pa[i] = load8_f32_to_bf16((const float*)Ap + (size_t)(bm + ra) * K + kn);
                else
                    pa[i] = *(const bf16x8*)((const ushort_t*)Ap + (size_t)(bm + ra) * K + kn);
                if constexpr (B_F32)
                    pb[i] = load8_f32_to_bf16((const float*)Bp + (size_t)(bn + ra) * K + kn);
                else
                    pb[i] = *(const bf16x8*)((const ushort_t*)Bp + (size_t)(bn + ra) * K + kn);
            }
        }

#pragma unroll
        for (int ks = 0; ks < BK; ks += 32) {
            bf16x8 af[4], bfr[4];
#pragma unroll
            for (int i = 0; i < 4; i++)
                af[i] = *(const bf16x8*)&As[(wm + i * 16 + l16) * LDK + ks + quad * 8];
#pragma unroll
            for (int i = 0; i < 4; i++)
                bfr[i] = *(const bf16x8*)&Bs[(wn + i * 16 + l16) * LDK + ks + quad * 8];
#pragma unroll
            for (int mi = 0; mi < 4; mi++)
#pragma unroll
                for (int ni = 0; ni < 4; ni++)
                    acc[mi][ni] = __builtin_amdgcn_mfma_f32_16x16x32_bf16(
                        af[mi], bfr[ni], acc[mi][ni], 0, 0, 0);
        }
    }

#pragma unroll
    for (int mi = 0; mi < 4; mi++) {
        const int row0 = bm + wm + mi * 16 + quad * 4;
#pragma unroll
        for (int r = 0; r < 4; r++) {
            const int row = row0 + r;
            if constexpr (EPI == 1) {
                float* crow = (float*)Cp + (size_t)row * N + bn + wn;
#pragma unroll
                for (int ni = 0; ni < 4; ni++)
                    crow[ni * 16 + l16] = acc[mi][ni][r];
            } else {
                if (bn < 2048) {
                    const float qs = (bn < 1024) ? QK_LOG2E_SCALE : 1.0f;
                    ushort_t* crow = (ushort_t*)Cp + (size_t)row * 2048 + bn + wn;
#pragma unroll
                    for (int ni = 0; ni < 4; ni++)
                        crow[ni * 16 + l16] = f2bf(acc[mi][ni][r] * qs);
                } else {
                    ushort_t* vt = (ushort_t*)Cp2;
                    const int bb = row >> 11, tt = row & 2047;
#pragma unroll
                    for (int ni = 0; ni < 4; ni++) {
                        const int vc = bn + wn + ni * 16 + l16 - 2048;
                        const int hh = vc >> 6, dd = vc & 63;
                        vt[(((size_t)bb * 16 + hh) * 64 + dd) * 2048 + tt] =
                            f2bf(acc[mi][ni][r]);
                    }
                }
            }
        }
    }
}

// ---------------------------------------------------------------------------
// attn4: causal flash attention, 128 q-rows per block, static-max exp2
// softmax. Ps columns rotated by quad*16 so the C-layout b16 stores spread
// across all 32 banks (was 4-way conflicted); A-frag reads un-rotate by
// (l16>>2)*16 and stay 16B-aligned b128.
// ---------------------------------------------------------------------------
#define AT_T 2048
#define PLD 72   // Ps leading dim (144B rows, 16B aligned)

__global__ __launch_bounds__(256) void attn4(
        const ushort_t* __restrict__ qk,
        const ushort_t* __restrict__ vt,
        ushort_t* __restrict__ attout) {
    const int bh   = blockIdx.x;                   // 0..63 (fastest)
    const int qblk = (gridDim.y - 1) - blockIdx.y; // 15..0, longest first
    const int b    = bh >> 4;
    const int h    = bh & 15;

    const int tid  = threadIdx.x;
    const int lane = tid & 63;
    const int w    = tid >> 6;
    const int quad = lane >> 4;
    const int l16  = lane & 15;
    const int sw   = l16 & 7;

    __shared__ ushort_t Ks[64 * 64];    // unpadded, XOR-swizzled
    __shared__ ushort_t Vs[80 * 64];    // rows 0..63 V^T tile; 64 ones; 65+ zero
    __shared__ ushort_t Ps[4][32 * PLD];

    for (int i = tid; i < 16 * 64; i += 256) Vs[64 * 64 + i] = 0;
    if (tid < 64) Vs[64 * 64 + tid] = 0x3F80;   // bf16 1.0

    const ushort_t* qp = qk + (size_t)b * AT_T * 2048 + h * 64;
    const ushort_t* kp = qp + 1024;
    const ushort_t* vp = vt + (size_t)bh * 64 * 2048;

    const int Q0 = qblk * 128 + w * 16;   // strip0 base row; strip1 = Q0+64

    bf16x8 aq[2][2];
#pragma unroll
    for (int s = 0; s < 2; s++) {
        const ushort_t* qrow = qp + (size_t)(Q0 + s * 64 + l16) * 2048;
        aq[s][0] = *(const bf16x8*)(qrow + quad * 8);
        aq[s][1] = *(const bf16x8*)(qrow + 32 + quad * 8);
    }

    f32x4 o[2][5] = {};   // [strip][0..3 = out cols, 4 = l ones-column]

    const int lr8 = lane >> 3;
    const int cbg = ((lane & 7) ^ lr8) * 8;

    const int nk = 2 * qblk + 2;
    for (int kt = 0; kt < nk; kt++) {
        const int k0 = kt * 64;
        if (kt) __syncthreads();
#pragma unroll
        for (int j = 0; j < 2; j++) {
            gl2lds16(kp + (size_t)(k0 + w * 16 + j * 8 + lr8) * 2048 + cbg,
                     &Ks[(w * 16 + j * 8) * 64]);
            gl2lds16(vp + (size_t)(w * 16 + j * 8 + lr8) * 2048 + k0 + cbg,
                     &Vs[(w * 16 + j * 8) * 64]);
        }
        __syncthreads();

        f32x4 s0[4], s1[4];
#pragma unroll
        for (int c = 0; c < 4; c++) {
            s0[c][0] = -8.0f; s0[c][1] = -8.0f; s0[c][2] = -8.0f; s0[c][3] = -8.0f;
            s1[c] = s0[c];
#pragma unroll
            for (int ks = 0; ks < 2; ks++) {
                const int cs = ((quad + 4 * ks) ^ sw) * 8;
                bf16x8 bk = *(const bf16x8*)&Ks[(c * 16 + l16) * 64 + cs];
                s0[c] = __builtin_amdgcn_mfma_f32_16x16x32_bf16(aq[0][ks], bk, s0[c], 0, 0, 0);
                s1[c] = __builtin_amdgcn_mfma_f32_16x16x32_bf16(aq[1][ks], bk, s1[c], 0, 0, 0);
            }
        }

        if (kt >= 2 * qblk) {
            const int q0r = Q0 + quad * 4;
#pragma unroll
            for (int c = 0; c < 4; c++) {
                const int kcol = k0 + c * 16 + l16;
#pragma unroll
                for (int r = 0; r < 4; r++)
                    if (kcol > q0r + r) s0[c][r] = -__builtin_inff();
            }
        }
        if (kt == 2 * qblk + 1) {
            const int q1r = Q0 + 64 + quad * 4;
#pragma unroll
            for (int c = 0; c < 4; c++) {
                const int kcol = k0 + c * 16 + l16;
#pragma unroll
                for (int r = 0; r < 4; r++)
                    if (kcol > q1r + r) s1[c][r] = -__builtin_inff();
            }
        }

        // P = 2^s -> Ps with quad*16 column rotation (conflict-free stores)
#pragma unroll
        for (int c = 0; c < 4; c++) {
            const int colr = (c * 16 + l16 + quad * 16) & 63;
#pragma unroll
            for (int r = 0; r < 4; r++) {
                Ps[w][(quad * 4 + r) * PLD + colr] = f2bf_fast(EXP2(s0[c][r]));
                Ps[w][(16 + quad * 4 + r) * PLD + colr] = f2bf_fast(EXP2(s1[c][r]));
            }
        }

        __asm__ __volatile__("s_waitcnt lgkmcnt(0)" ::: "memory");

        // O += P @ V (bv shared across strips; n=4 = ones column -> l)
#pragma unroll
        for (int ks = 0; ks < 2; ks++) {
            const int cs  = ((quad + 4 * ks) ^ sw) * 8;
            const int pst = (ks * 32 + quad * 8 + (l16 >> 2) * 16) & 63;  // un-rotate
            bf16x8 ap0 = *(const bf16x8*)&Ps[w][l16 * PLD + pst];
            bf16x8 ap1 = *(const bf16x8*)&Ps[w][(16 + l16) * PLD + pst];
#pragma unroll
            for (int n = 0; n < 5; n++) {
                bf16x8 bv = *(const bf16x8*)&Vs[(n * 16 + l16) * 64 + cs];
                o[0][n] = __builtin_amdgcn_mfma_f32_16x16x32_bf16(ap0, bv, o[0][n], 0, 0, 0);
                o[1][n] = __builtin_amdgcn_mfma_f32_16x16x32_bf16(ap1, bv, o[1][n], 0, 0, 0);
            }
        }
    }

#pragma unroll
    for (int s = 0; s < 2; s++) {
        ushort_t* op = attout + (size_t)(b * AT_T + Q0 + s * 64 + quad * 4) * 1024 + h * 64;
#pragma unroll
        for (int r = 0; r < 4; r++) {
            const float l = __shfl(o[s][4][r], lane & 48, 64);
            const float inv = 1.0f / fmaxf(l, 1e-30f);
            ushort_t* orow = op + (size_t)r * 1024;
#pragma unroll
            for (int n = 0; n < 4; n++)
                orow[n * 16 + l16] = f2bf(o[s][n][r] * inv);
        }
    }
}

// ---------------------------------------------------------------------------
extern "C" void kernel_launch(void* const* d_in, const int* in_sizes, int n_in,
                              void* d_out, int out_size, void* d_ws, size_t ws_size,
                              hipStream_t stream) {
    const float* x      = (const float*)d_in[0];
    const float* w_attn = (const float*)d_in[1];
    const float* w_proj = (const float*)d_in[2];
    float* out = (float*)d_out;

    const int M = 8192, C = 1024;
    const size_t E_QK  = (size_t)M * 2048;
    const size_t E_VT  = (size_t)4 * 16 * 64 * 2048;
    const size_t E_ATT = (size_t)M * 1024;
    const size_t E_X   = (size_t)M * 1024;
    const size_t E_WA  = (size_t)3072 * 1024;
    const size_t E_WP  = (size_t)1024 * 1024;
    const size_t need_mid  = (E_QK + E_VT + E_ATT) * 2;
    const size_t need_full = need_mid + (E_X + E_WA + E_WP) * 2;

    if (ws_size < need_mid) {
        fill_zero_f32<<<(out_size + 255) / 256, 256, 0, stream>>>(out, out_size);
        return;
    }

    ushort_t* qk  = (ushort_t*)d_ws;
    ushort_t* vt  = qk + E_QK;
    ushort_t* att = vt + E_VT;

    if (ws_size >= need_full) {
        ushort_t* xb  = att + E_ATT;   // xb, wab, wpb contiguous
        const long n8x = (long)(E_X / 8), n8a = (long)(E_WA / 8), n8p = (long)(E_WP / 8);
        const long n8  = n8x + n8a + n8p;
        cvt3<<<(int)((n8 + 255) / 256), 256, 0, stream>>>(
            x, n8x, w_attn, n8a, w_proj, n8p, xb);

        ushort_t* wab = xb + E_X;
        ushort_t* wpb = wab + E_WA;
        gemm_lds<2><<<dim3(3 * C / BN, M / BM), 256, 0, stream>>>(
            xb, wab, qk, vt, M, 3 * C, C);
        attn4<<<dim3(64, 16), 256, 0, stream>>>(qk, vt, att);
        gemm_lds<1><<<dim3(C / BN, M / BM), 256, 0, stream>>>(
            att, wpb, out, nullptr, M, C, C);
    } else {
        gemm_nt<true, true, 2><<<dim3(3 * C / BN, M / BM), 256, 0, stream>>>(
            x, w_attn, qk, vt, M, 3 * C, C);
        attn4<<<dim3(64, 16), 256, 0, stream>>>(qk, vt, att);
        gemm_nt<false, true, 1><<<dim3(C / BN, M / BM), 256, 0, stream>>>(
            att, w_proj, out, nullptr, M, C, C);
    }
}